// Round 7
// baseline (526.773 us; speedup 1.0000x reference)
//
#include <hip/hip_runtime.h>
#include <hip/hip_bf16.h>

typedef __attribute__((ext_vector_type(8))) short short8;
typedef __attribute__((ext_vector_type(4))) float floatx4;

#define BM 128
#define BN 128
#define BK 64
#define LDS_PAD 24
#define LDS_STRIDE (BK + LDS_PAD)

#define G_CHUNKS 128
#define T_CHUNK 16
#define L2E 1.44269504f

__device__ __forceinline__ float bf2f(short v) {
    return __builtin_bit_cast(float, ((unsigned)(unsigned short)v) << 16);
}
__device__ __forceinline__ unsigned short f2bfbits(float f) {
    return __builtin_bit_cast(unsigned short, __float2bfloat16(f));
}

// ---------------- GEMM (plain): C[m,n] = sum_k A[m,k]*W[n,k], A bf16, W f32 staged->bf16 ----------------
template <typename OUT_T>
__global__ __launch_bounds__(256) void gemm_bt(
    const __hip_bfloat16* __restrict__ A, const float* __restrict__ W,
    OUT_T* __restrict__ C, int N, int K, int lda, int ldw, int ldc)
{
    __shared__ __align__(16) __hip_bfloat16 As[BM * LDS_STRIDE];
    __shared__ __align__(16) __hip_bfloat16 Ws[BN * LDS_STRIDE];
    const int tid  = threadIdx.x;
    const int bm   = blockIdx.x * BM;
    const int bn   = blockIdx.y * BN;
    const int lane = tid & 63;
    const int wid  = tid >> 6;
    const int wm   = (wid >> 1) * 64;
    const int wn   = (wid & 1) * 64;
    const int l15  = lane & 15;
    const int quad = lane >> 4;

    floatx4 acc[4][4];
#pragma unroll
    for (int i = 0; i < 4; ++i)
#pragma unroll
        for (int j = 0; j < 4; ++j)
#pragma unroll
            for (int r = 0; r < 4; ++r) acc[i][j][r] = 0.f;

    const int lrow = tid >> 3;
    const int lcol = (tid & 7) * 8;

    for (int k0 = 0; k0 < K; k0 += BK) {
#pragma unroll
        for (int r = 0; r < 4; ++r) {
            const int row = r * 32 + lrow;
            const uint4 va = *reinterpret_cast<const uint4*>(A + (size_t)(bm + row) * lda + k0 + lcol);
            *reinterpret_cast<uint4*>(&As[row * LDS_STRIDE + lcol]) = va;
            const int n = bn + row;
            __align__(16) unsigned short wb[8];
            const float4 f0 = *reinterpret_cast<const float4*>(W + (size_t)n * ldw + k0 + lcol);
            const float4 f1 = *reinterpret_cast<const float4*>(W + (size_t)n * ldw + k0 + lcol + 4);
            wb[0] = f2bfbits(f0.x); wb[1] = f2bfbits(f0.y);
            wb[2] = f2bfbits(f0.z); wb[3] = f2bfbits(f0.w);
            wb[4] = f2bfbits(f1.x); wb[5] = f2bfbits(f1.y);
            wb[6] = f2bfbits(f1.z); wb[7] = f2bfbits(f1.w);
            *reinterpret_cast<uint4*>(&Ws[row * LDS_STRIDE + lcol]) = *reinterpret_cast<const uint4*>(wb);
        }
        __syncthreads();
#pragma unroll
        for (int kk = 0; kk < BK; kk += 32) {
            short8 af[4], bfr[4];
#pragma unroll
            for (int i = 0; i < 4; ++i)
                af[i] = *reinterpret_cast<const short8*>(&As[(wm + i * 16 + l15) * LDS_STRIDE + kk + quad * 8]);
#pragma unroll
            for (int j = 0; j < 4; ++j)
                bfr[j] = *reinterpret_cast<const short8*>(&Ws[(wn + j * 16 + l15) * LDS_STRIDE + kk + quad * 8]);
#pragma unroll
            for (int i = 0; i < 4; ++i)
#pragma unroll
                for (int j = 0; j < 4; ++j)
                    acc[i][j] = __builtin_amdgcn_mfma_f32_16x16x32_bf16(af[i], bfr[j], acc[i][j], 0, 0, 0);
        }
        __syncthreads();
    }

#pragma unroll
    for (int i = 0; i < 4; ++i) {
#pragma unroll
        for (int j = 0; j < 4; ++j) {
            const int col = bn + wn + j * 16 + l15;
#pragma unroll
            for (int r = 0; r < 4; ++r) {
                const int rowg = bm + wm + i * 16 + quad * 4 + r;
                if constexpr (sizeof(OUT_T) == 4)
                    C[(size_t)rowg * ldc + col] = acc[i][j][r];
                else
                    C[(size_t)rowg * ldc + col] = __float2bfloat16(acc[i][j][r]);
            }
        }
    }
}

// ---------------- dt GEMM: A = xdblF f32 [4096][96] (k=0..63), W f32 [2048][64], softplus, out [t][d] bf16 ----------------
__global__ __launch_bounds__(256) void gemm_dt64(
    const float* __restrict__ A, const float* __restrict__ W,
    const float* __restrict__ bias, __hip_bfloat16* __restrict__ C)
{
    __shared__ __align__(16) __hip_bfloat16 As[BM * LDS_STRIDE];
    __shared__ __align__(16) __hip_bfloat16 Ws[BN * LDS_STRIDE];
    const int tid  = threadIdx.x;
    const int bm   = blockIdx.x * BM;
    const int bn   = blockIdx.y * BN;
    const int lane = tid & 63;
    const int wid  = tid >> 6;
    const int wm   = (wid >> 1) * 64;
    const int wn   = (wid & 1) * 64;
    const int l15  = lane & 15;
    const int quad = lane >> 4;
    const int lrow = tid >> 3;
    const int lcol = (tid & 7) * 8;

#pragma unroll
    for (int r = 0; r < 4; ++r) {
        const int row = r * 32 + lrow;
        __align__(16) unsigned short ab[8];
        const float4 a0 = *reinterpret_cast<const float4*>(A + (size_t)(bm + row) * 96 + lcol);
        const float4 a1 = *reinterpret_cast<const float4*>(A + (size_t)(bm + row) * 96 + lcol + 4);
        ab[0] = f2bfbits(a0.x); ab[1] = f2bfbits(a0.y);
        ab[2] = f2bfbits(a0.z); ab[3] = f2bfbits(a0.w);
        ab[4] = f2bfbits(a1.x); ab[5] = f2bfbits(a1.y);
        ab[6] = f2bfbits(a1.z); ab[7] = f2bfbits(a1.w);
        *reinterpret_cast<uint4*>(&As[row * LDS_STRIDE + lcol]) = *reinterpret_cast<const uint4*>(ab);

        const int n = bn + row;
        __align__(16) unsigned short wb[8];
        const float4 f0 = *reinterpret_cast<const float4*>(W + (size_t)n * 64 + lcol);
        const float4 f1 = *reinterpret_cast<const float4*>(W + (size_t)n * 64 + lcol + 4);
        wb[0] = f2bfbits(f0.x); wb[1] = f2bfbits(f0.y);
        wb[2] = f2bfbits(f0.z); wb[3] = f2bfbits(f0.w);
        wb[4] = f2bfbits(f1.x); wb[5] = f2bfbits(f1.y);
        wb[6] = f2bfbits(f1.z); wb[7] = f2bfbits(f1.w);
        *reinterpret_cast<uint4*>(&Ws[row * LDS_STRIDE + lcol]) = *reinterpret_cast<const uint4*>(wb);
    }
    __syncthreads();

    floatx4 acc[4][4];
#pragma unroll
    for (int i = 0; i < 4; ++i)
#pragma unroll
        for (int j = 0; j < 4; ++j)
#pragma unroll
            for (int r = 0; r < 4; ++r) acc[i][j][r] = 0.f;

#pragma unroll
    for (int kk = 0; kk < BK; kk += 32) {
        short8 af[4], bfr[4];
#pragma unroll
        for (int i = 0; i < 4; ++i)
            af[i] = *reinterpret_cast<const short8*>(&As[(wm + i * 16 + l15) * LDS_STRIDE + kk + quad * 8]);
#pragma unroll
        for (int j = 0; j < 4; ++j)
            bfr[j] = *reinterpret_cast<const short8*>(&Ws[(wn + j * 16 + l15) * LDS_STRIDE + kk + quad * 8]);
#pragma unroll
        for (int i = 0; i < 4; ++i)
#pragma unroll
            for (int j = 0; j < 4; ++j)
                acc[i][j] = __builtin_amdgcn_mfma_f32_16x16x32_bf16(af[i], bfr[j], acc[i][j], 0, 0, 0);
    }

#pragma unroll
    for (int i = 0; i < 4; ++i) {
#pragma unroll
        for (int j = 0; j < 4; ++j) {
            const int col = bn + wn + j * 16 + l15;
            const float bv = bias[col];
#pragma unroll
            for (int r = 0; r < 4; ++r) {
                const int rowg = bm + wm + i * 16 + quad * 4 + r;
                float v = acc[i][j][r] + bv;
                v = (v > 20.f) ? v : log1pf(__expf(v));
                C[(size_t)rowg * 2048 + col] = __float2bfloat16(v);
            }
        }
    }
}

// ---------------- LayerNorm + residual ----------------
__global__ __launch_bounds__(256) void ln_res_kernel(
    const float* __restrict__ x,
    const float* __restrict__ nw, const float* __restrict__ nb,
    __hip_bfloat16* __restrict__ h, float* __restrict__ res)
{
    const int row = blockIdx.x;
    const int tid = threadIdx.x;
    const float* xr = x + (size_t)row * 1024;
    float v[4];
    float sum = 0.f, sumsq = 0.f;
#pragma unroll
    for (int i = 0; i < 4; ++i) {
        const float f = xr[tid + i * 256];
        v[i] = f; sum += f; sumsq += f * f;
    }
#pragma unroll
    for (int off = 32; off > 0; off >>= 1) {
        sum   += __shfl_down(sum, off);
        sumsq += __shfl_down(sumsq, off);
    }
    __shared__ float ssum[4], ssq[4];
    const int w = tid >> 6, lane = tid & 63;
    if (lane == 0) { ssum[w] = sum; ssq[w] = sumsq; }
    __syncthreads();
    sum   = ssum[0] + ssum[1] + ssum[2] + ssum[3];
    sumsq = ssq[0] + ssq[1] + ssq[2] + ssq[3];
    const float mu  = sum * (1.f / 1024.f);
    const float var = sumsq * (1.f / 1024.f) - mu * mu;
    const float rs  = rsqrtf(var + 1e-5f);
#pragma unroll
    for (int i = 0; i < 4; ++i) {
        const int c = tid + i * 256;
        const float hn = (v[i] - mu) * rs * nw[c] + nb[c];
        h[(size_t)row * 1024 + c]   = __float2bfloat16(hn);
        res[(size_t)row * 1024 + c] = v[i];
    }
}

// ---------------- conv(width4,causal)+SiLU -> u[t,d]; silu(z) -> sz[t,d] (8t x 8d per thread) ----------------
__global__ __launch_bounds__(256) void conv_td(
    const __hip_bfloat16* __restrict__ xz,
    const float* __restrict__ conv_w, const float* __restrict__ conv_b,
    __hip_bfloat16* __restrict__ ub, __hip_bfloat16* __restrict__ szb)
{
    const int t0 = blockIdx.x * 8;          // 512 blocks; 8|2048 so tiles never cross batch
    const int d8 = threadIdx.x * 8;
    const int l0 = t0 & 2047;
    short8 xr[11];
#pragma unroll
    for (int i = 0; i < 11; ++i) {
        short8 v = {0, 0, 0, 0, 0, 0, 0, 0};
        if (l0 + i - 3 >= 0)
            v = *reinterpret_cast<const short8*>(xz + (size_t)(t0 + i - 3) * 4096 + d8);
        xr[i] = v;
    }
    float w[8][4], bias[8];
    {
        const float4* wp = reinterpret_cast<const float4*>(conv_w + (size_t)d8 * 4);
#pragma unroll
        for (int dd = 0; dd < 8; ++dd) {
            const float4 wv = wp[dd];
            w[dd][0] = wv.x; w[dd][1] = wv.y; w[dd][2] = wv.z; w[dd][3] = wv.w;
        }
        const float4* bp = reinterpret_cast<const float4*>(conv_b + d8);
        const float4 b0 = bp[0], b1 = bp[1];
        bias[0] = b0.x; bias[1] = b0.y; bias[2] = b0.z; bias[3] = b0.w;
        bias[4] = b1.x; bias[5] = b1.y; bias[6] = b1.z; bias[7] = b1.w;
    }
#pragma unroll
    for (int tt = 0; tt < 8; ++tt) {
        const short8 zv = *reinterpret_cast<const short8*>(xz + (size_t)(t0 + tt) * 4096 + 2048 + d8);
        __align__(16) unsigned short uo[8], zo[8];
#pragma unroll
        for (int dd = 0; dd < 8; ++dd) {
            float a = bias[dd];
            a = fmaf(bf2f(xr[tt + 0][dd]), w[dd][0], a);
            a = fmaf(bf2f(xr[tt + 1][dd]), w[dd][1], a);
            a = fmaf(bf2f(xr[tt + 2][dd]), w[dd][2], a);
            a = fmaf(bf2f(xr[tt + 3][dd]), w[dd][3], a);
            uo[dd] = f2bfbits(a / (1.f + __expf(-a)));
            const float z = bf2f(zv[dd]);
            zo[dd] = f2bfbits(z / (1.f + __expf(-z)));
        }
        *reinterpret_cast<uint4*>(ub  + (size_t)(t0 + tt) * 2048 + d8) = *reinterpret_cast<const uint4*>(uo);
        *reinterpret_cast<uint4*>(szb + (size_t)(t0 + tt) * 2048 + d8) = *reinterpret_cast<const uint4*>(zo);
    }
}

// ---------------- x_proj, split-K; output xdblF f32 [t][96] ----------------
__global__ __launch_bounds__(256) void wt_prep(const float* __restrict__ W, float* __restrict__ WT)
{
    const int idx = blockIdx.x * 256 + threadIdx.x;    // 196608
    const int k = idx / 96, n = idx - k * 96;
    WT[idx] = W[(size_t)n * 2048 + k];
}

__global__ __launch_bounds__(256) void xproj_partial(
    const __hip_bfloat16* __restrict__ ub, const float* __restrict__ WT,
    float* __restrict__ part)
{
    const int m  = blockIdx.y * 256 + threadIdx.x;
    const int n0 = blockIdx.x * 4;
    const int c  = blockIdx.z;
    const short8* up = reinterpret_cast<const short8*>(ub + (size_t)m * 2048 + c * 256);
    const float* wt = WT + (size_t)c * 256 * 96 + n0;
    float a0 = 0.f, a1 = 0.f, a2 = 0.f, a3 = 0.f;
    for (int t = 0; t < 32; ++t) {
        const short8 uv = up[t];
#pragma unroll
        for (int k = 0; k < 8; ++k) {
            const float4 wv = *reinterpret_cast<const float4*>(wt + (size_t)(t * 8 + k) * 96);
            const float f = bf2f(uv[k]);
            a0 = fmaf(f, wv.x, a0);
            a1 = fmaf(f, wv.y, a1);
            a2 = fmaf(f, wv.z, a2);
            a3 = fmaf(f, wv.w, a3);
        }
    }
    float* pp = part + ((size_t)c * 96 + n0) * 4096 + m;
    pp[0]        = a0;
    pp[4096]     = a1;
    pp[2 * 4096] = a2;
    pp[3 * 4096] = a3;
}

__global__ __launch_bounds__(256) void xproj_reduce(
    const float* __restrict__ part, float* __restrict__ xdblF)
{
    const int idx = blockIdx.x * 256 + threadIdx.x;    // n*4096 + m, 393216
    const int n = idx >> 12, m = idx & 4095;
    float s = 0.f;
#pragma unroll
    for (int c = 0; c < 8; ++c)
        s += part[((size_t)c * 96 + n) * 4096 + m];
    xdblF[(size_t)m * 96 + n] = s;
}

// ---------------- state-in-lane chunked scan: lane = channel, 16 states in VGPRs ----------------
// grid 2048: c = bx>>4 (chunk 0..127), bd = (bx&15)*256 + tid; b = bd>>11, d = bd&2047; rows b*2048 + c*16 + t.
__global__ __launch_bounds__(256) void scan_phase1(
    const __hip_bfloat16* __restrict__ dtb, const __hip_bfloat16* __restrict__ ub,
    const float* __restrict__ xdblF, const float* __restrict__ A_log,
    __hip_bfloat16* __restrict__ Sbuf, float* __restrict__ sdtb)
{
    const int tid = threadIdx.x;
    const int c   = blockIdx.x >> 4;
    const int bd  = ((blockIdx.x & 15) << 8) + tid;
    const int b   = bd >> 11;
    const int d   = bd & 2047;
    const int row0 = b * 2048 + c * T_CHUNK;

    float As[16];
    {
        const float4* ap = reinterpret_cast<const float4*>(A_log + (size_t)d * 16);
#pragma unroll
        for (int i = 0; i < 4; ++i) {
            const float4 a = ap[i];
            As[4 * i + 0] = -__expf(a.x) * L2E;
            As[4 * i + 1] = -__expf(a.y) * L2E;
            As[4 * i + 2] = -__expf(a.z) * L2E;
            As[4 * i + 3] = -__expf(a.w) * L2E;
        }
    }
    float S[16];
#pragma unroll
    for (int s = 0; s < 16; ++s) S[s] = 0.f;
    float sdt = 0.f;

#pragma unroll 4
    for (int t = 0; t < T_CHUNK; ++t) {
        const size_t row = (size_t)(row0 + t);
        const float dtv = __bfloat162float(dtb[row * 2048 + d]);
        const float uu  = __bfloat162float(ub[row * 2048 + d]);
        const float dtu = dtv * uu;
        sdt += dtv;
        const float4* bq = reinterpret_cast<const float4*>(xdblF + row * 96 + 64);
#pragma unroll
        for (int i = 0; i < 4; ++i) {
            const float4 Bf = bq[i];
            float dA;
            dA = exp2f(dtv * As[4 * i + 0]); S[4 * i + 0] = fmaf(dA, S[4 * i + 0], dtu * Bf.x);
            dA = exp2f(dtv * As[4 * i + 1]); S[4 * i + 1] = fmaf(dA, S[4 * i + 1], dtu * Bf.y);
            dA = exp2f(dtv * As[4 * i + 2]); S[4 * i + 2] = fmaf(dA, S[4 * i + 2], dtu * Bf.z);
            dA = exp2f(dtv * As[4 * i + 3]); S[4 * i + 3] = fmaf(dA, S[4 * i + 3], dtu * Bf.w);
        }
    }
    __align__(16) unsigned short pk[16];
#pragma unroll
    for (int s = 0; s < 16; ++s) pk[s] = f2bfbits(S[s]);
    __hip_bfloat16* sp = Sbuf + ((size_t)c * 4096 + bd) * 16;
    *reinterpret_cast<uint4*>(sp)     = *reinterpret_cast<const uint4*>(pk);
    *reinterpret_cast<uint4*>(sp + 8) = *reinterpret_cast<const uint4*>(pk + 8);
    sdtb[(size_t)c * 4096 + bd] = sdt;
}

// Serial combine across 128 chunks; in-place S -> Hinit (read S[c] before writing Hinit[c], same address).
__global__ __launch_bounds__(256) void scan_phase2(
    __hip_bfloat16* SH, const float* __restrict__ sdtb, const float* __restrict__ A_log)
{
    const int idx = blockIdx.x * 256 + threadIdx.x;   // 65536
    const int bd = idx >> 4, s = idx & 15;
    const int d = bd & 2047;
    const float As = -__expf(A_log[(size_t)d * 16 + s]) * L2E;
    float h = 0.f;
#pragma unroll 4
    for (int c = 0; c < G_CHUNKS; ++c) {
        const size_t ix = ((size_t)c * 4096 + bd) * 16 + s;
        const float Sv  = __bfloat162float(SH[ix]);
        const float sdt = sdtb[(size_t)c * 4096 + bd];
        SH[ix] = __float2bfloat16(h);
        h = fmaf(exp2f(As * sdt), h, Sv);
    }
}

// Full scan from Hinit + fused D-skip and gating. y aliases dtb (dt loads hoisted) -> no restrict there.
__global__ __launch_bounds__(256) void scan_phase3(
    const __hip_bfloat16* dtb,
    const __hip_bfloat16* __restrict__ ub, const __hip_bfloat16* __restrict__ szb,
    const float* __restrict__ xdblF, const float* __restrict__ A_log,
    const float* __restrict__ Dw, const __hip_bfloat16* __restrict__ Hinit,
    __hip_bfloat16* yb)
{
    const int tid = threadIdx.x;
    const int c   = blockIdx.x >> 4;
    const int bd  = ((blockIdx.x & 15) << 8) + tid;
    const int b   = bd >> 11;
    const int d   = bd & 2047;
    const int row0 = b * 2048 + c * T_CHUNK;

    float As[16];
    {
        const float4* ap = reinterpret_cast<const float4*>(A_log + (size_t)d * 16);
#pragma unroll
        for (int i = 0; i < 4; ++i) {
            const float4 a = ap[i];
            As[4 * i + 0] = -__expf(a.x) * L2E;
            As[4 * i + 1] = -__expf(a.y) * L2E;
            As[4 * i + 2] = -__expf(a.z) * L2E;
            As[4 * i + 3] = -__expf(a.w) * L2E;
        }
    }
    float h[16];
    {
        const short8* hp = reinterpret_cast<const short8*>(Hinit + ((size_t)c * 4096 + bd) * 16);
        const short8 h0 = hp[0], h1 = hp[1];
#pragma unroll
        for (int s = 0; s < 8; ++s) { h[s] = bf2f(h0[s]); h[8 + s] = bf2f(h1[s]); }
    }
    const float Dv = Dw[d];

    // hoist dt loads: yb aliases dtb, loading all 16 up-front removes the false store->load dependency
    unsigned short dtr[16];
#pragma unroll
    for (int t = 0; t < T_CHUNK; ++t)
        dtr[t] = __builtin_bit_cast(unsigned short, dtb[(size_t)(row0 + t) * 2048 + d]);

#pragma unroll 4
    for (int t = 0; t < T_CHUNK; ++t) {
        const size_t row = (size_t)(row0 + t);
        const float dtv = bf2f((short)dtr[t]);
        const float uu  = __bfloat162float(ub[row * 2048 + d]);
        const float szv = __bfloat162float(szb[row * 2048 + d]);
        const float dtu = dtv * uu;
        const float4* bq = reinterpret_cast<const float4*>(xdblF + row * 96 + 64);
        const float4* cq = reinterpret_cast<const float4*>(xdblF + row * 96 + 80);
        float y0 = 0.f, y1 = 0.f;
#pragma unroll
        for (int i = 0; i < 4; ++i) {
            const float4 Bf = bq[i];
            const float4 Cf = cq[i];
            float dA;
            dA = exp2f(dtv * As[4 * i + 0]); h[4 * i + 0] = fmaf(dA, h[4 * i + 0], dtu * Bf.x); y0 = fmaf(h[4 * i + 0], Cf.x, y0);
            dA = exp2f(dtv * As[4 * i + 1]); h[4 * i + 1] = fmaf(dA, h[4 * i + 1], dtu * Bf.y); y1 = fmaf(h[4 * i + 1], Cf.y, y1);
            dA = exp2f(dtv * As[4 * i + 2]); h[4 * i + 2] = fmaf(dA, h[4 * i + 2], dtu * Bf.z); y0 = fmaf(h[4 * i + 2], Cf.z, y0);
            dA = exp2f(dtv * As[4 * i + 3]); h[4 * i + 3] = fmaf(dA, h[4 * i + 3], dtu * Bf.w); y1 = fmaf(h[4 * i + 3], Cf.w, y1);
        }
        const float yy = fmaf(uu, Dv, y0 + y1) * szv;
        yb[row * 2048 + d] = __float2bfloat16(yy);
    }
}

extern "C" void kernel_launch(void* const* d_in, const int* in_sizes, int n_in,
                              void* d_out, int out_size, void* d_ws, size_t ws_size,
                              hipStream_t stream)
{
    const float* x          = (const float*)d_in[0];
    const float* in_proj_w  = (const float*)d_in[1];
    const float* conv_w     = (const float*)d_in[2];
    const float* conv_b     = (const float*)d_in[3];
    const float* x_proj_w   = (const float*)d_in[4];
    const float* dt_proj_w  = (const float*)d_in[5];
    const float* dt_proj_b  = (const float*)d_in[6];
    const float* A_log      = (const float*)d_in[7];
    const float* Dw         = (const float*)d_in[8];
    const float* out_proj_w = (const float*)d_in[9];
    const float* norm_w     = (const float*)d_in[10];
    const float* norm_b     = (const float*)d_in[11];

    float* out = (float*)d_out;
    float* res = out + 4194304;
    char* ws = (char*)d_ws;
    // Region A [0, 8.39M): h (dead after gemm1) -> xdblF + WT + sdt
    __hip_bfloat16* h      = (__hip_bfloat16*)(ws);                      // 8,388,608 B
    float*          xdblF  = (float*)(ws);                               // 4096*96*4 = 1,572,864
    float*          WT     = (float*)(ws + 1572864);                     // 786,432
    float*          sdtb   = (float*)(ws + 2359296);                     // 128*4096*4 = 2,097,152 (ends 4,456,448)
    // Region B [8.39M, 41.94M): xz (dead after conv) -> part (dead after reduce) -> dt(+y alias) + S/Hinit
    __hip_bfloat16* xz     = (__hip_bfloat16*)(ws + 8388608);            // 32M
    float*          part   = (float*)(ws + 8388608);                     // 12.6M
    __hip_bfloat16* dtb    = (__hip_bfloat16*)(ws + 8388608);            // 16M
    __hip_bfloat16* Sbuf   = (__hip_bfloat16*)(ws + 25165824);           // 16M (Hinit in-place)
    __hip_bfloat16* y      = dtb;                                        // alias (phase3 hoists dt loads)
    // Regions C/D
    __hip_bfloat16* ub     = (__hip_bfloat16*)(ws + 41943040);           // 16M
    __hip_bfloat16* szb    = (__hip_bfloat16*)(ws + 58720256);           // 16M

    // 1. LayerNorm + residual
    ln_res_kernel<<<4096, 256, 0, stream>>>(x, norm_w, norm_b, h, res);
    // 2. xz = h @ in_proj_w^T   (4096x4096x1024)
    gemm_bt<__hip_bfloat16><<<dim3(32, 32), 256, 0, stream>>>(h, in_proj_w, xz, 4096, 1024, 1024, 1024, 4096);
    // 3. u = silu(conv(xz[:,:2048])), sz = silu(xz[:,2048:])   [t,d] layout; xz dead after
    conv_td<<<512, 256, 0, stream>>>(xz, conv_w, conv_b, ub, szb);
    // 4. xdblF = u @ x_proj_w^T  f32 [t][96], split-K
    wt_prep<<<768, 256, 0, stream>>>(x_proj_w, WT);
    xproj_partial<<<dim3(24, 16, 8), 256, 0, stream>>>(ub, WT, part);
    xproj_reduce<<<1536, 256, 0, stream>>>(part, xdblF);
    // 5. dt = softplus(xdblF[:, :64] @ dt_proj_w^T + b)  [t][d]
    gemm_dt64<<<dim3(32, 16), 256, 0, stream>>>(xdblF, dt_proj_w, dt_proj_b, dtb);
    // 6. state-in-lane chunked scan (G=128, T=16)
    scan_phase1<<<2048, 256, 0, stream>>>(dtb, ub, xdblF, A_log, Sbuf, sdtb);
    scan_phase2<<<256, 256, 0, stream>>>(Sbuf, sdtb, A_log);
    scan_phase3<<<2048, 256, 0, stream>>>(dtb, ub, szb, xdblF, A_log, Dw, Sbuf, y);
    // 7. out = y @ out_proj_w^T  (4096x1024x2048) -> f32
    gemm_bt<float><<<dim3(32, 8), 256, 0, stream>>>(y, out_proj_w, out, 1024, 2048, 2048, 2048, 1024);
}

// Round 8
// 424.637 us; speedup vs baseline: 1.2405x; 1.2405x over previous
//
#include <hip/hip_runtime.h>
#include <hip/hip_bf16.h>

typedef __attribute__((ext_vector_type(8))) short short8;
typedef __attribute__((ext_vector_type(4))) float floatx4;

#define BM 128
#define BN 128
#define BK 64
#define LDS_PAD 24
#define LDS_STRIDE (BK + LDS_PAD)

#define G_CHUNKS 128
#define T_CHUNK 16
#define L2E 1.44269504f

__device__ __forceinline__ float bf2f(short v) {
    return __builtin_bit_cast(float, ((unsigned)(unsigned short)v) << 16);
}
__device__ __forceinline__ unsigned short f2bfbits(float f) {
    return __builtin_bit_cast(unsigned short, __float2bfloat16(f));
}

// ---------------- GEMM (plain): C[m,n] = sum_k A[m,k]*W[n,k], A bf16, W f32 staged->bf16 ----------------
// N, M multiples of 128 here (no guards).
template <typename OUT_T>
__global__ __launch_bounds__(256) void gemm_bt(
    const __hip_bfloat16* __restrict__ A, const float* __restrict__ W,
    OUT_T* __restrict__ C, int N, int K, int lda, int ldw, int ldc)
{
    __shared__ __align__(16) __hip_bfloat16 As[BM * LDS_STRIDE];
    __shared__ __align__(16) __hip_bfloat16 Ws[BN * LDS_STRIDE];
    const int tid  = threadIdx.x;
    const int bm   = blockIdx.x * BM;
    const int bn   = blockIdx.y * BN;
    const int lane = tid & 63;
    const int wid  = tid >> 6;
    const int wm   = (wid >> 1) * 64;
    const int wn   = (wid & 1) * 64;
    const int l15  = lane & 15;
    const int quad = lane >> 4;

    floatx4 acc[4][4];
#pragma unroll
    for (int i = 0; i < 4; ++i)
#pragma unroll
        for (int j = 0; j < 4; ++j)
#pragma unroll
            for (int r = 0; r < 4; ++r) acc[i][j][r] = 0.f;

    const int lrow = tid >> 3;
    const int lcol = (tid & 7) * 8;

    for (int k0 = 0; k0 < K; k0 += BK) {
#pragma unroll
        for (int r = 0; r < 4; ++r) {
            const int row = r * 32 + lrow;
            const uint4 va = *reinterpret_cast<const uint4*>(A + (size_t)(bm + row) * lda + k0 + lcol);
            *reinterpret_cast<uint4*>(&As[row * LDS_STRIDE + lcol]) = va;
            const int n = bn + row;
            __align__(16) unsigned short wb[8];
            const float4 f0 = *reinterpret_cast<const float4*>(W + (size_t)n * ldw + k0 + lcol);
            const float4 f1 = *reinterpret_cast<const float4*>(W + (size_t)n * ldw + k0 + lcol + 4);
            wb[0] = f2bfbits(f0.x); wb[1] = f2bfbits(f0.y);
            wb[2] = f2bfbits(f0.z); wb[3] = f2bfbits(f0.w);
            wb[4] = f2bfbits(f1.x); wb[5] = f2bfbits(f1.y);
            wb[6] = f2bfbits(f1.z); wb[7] = f2bfbits(f1.w);
            *reinterpret_cast<uint4*>(&Ws[row * LDS_STRIDE + lcol]) = *reinterpret_cast<const uint4*>(wb);
        }
        __syncthreads();
#pragma unroll
        for (int kk = 0; kk < BK; kk += 32) {
            short8 af[4], bfr[4];
#pragma unroll
            for (int i = 0; i < 4; ++i)
                af[i] = *reinterpret_cast<const short8*>(&As[(wm + i * 16 + l15) * LDS_STRIDE + kk + quad * 8]);
#pragma unroll
            for (int j = 0; j < 4; ++j)
                bfr[j] = *reinterpret_cast<const short8*>(&Ws[(wn + j * 16 + l15) * LDS_STRIDE + kk + quad * 8]);
#pragma unroll
            for (int i = 0; i < 4; ++i)
#pragma unroll
                for (int j = 0; j < 4; ++j)
                    acc[i][j] = __builtin_amdgcn_mfma_f32_16x16x32_bf16(af[i], bfr[j], acc[i][j], 0, 0, 0);
        }
        __syncthreads();
    }

#pragma unroll
    for (int i = 0; i < 4; ++i) {
#pragma unroll
        for (int j = 0; j < 4; ++j) {
            const int col = bn + wn + j * 16 + l15;
#pragma unroll
            for (int r = 0; r < 4; ++r) {
                const int rowg = bm + wm + i * 16 + quad * 4 + r;
                if constexpr (sizeof(OUT_T) == 4)
                    C[(size_t)rowg * ldc + col] = acc[i][j][r];
                else
                    C[(size_t)rowg * ldc + col] = __float2bfloat16(acc[i][j][r]);
            }
        }
    }
}

// ---------------- x_proj MFMA split-K: part[c][m][96] = sum_{k in chunk c} ub[m,k]*W[n,k] ----------------
// grid (32 m-blocks, 8 k-chunks). A = ub bf16 [4096][2048]; W = x_proj_w f32 [96][2048].
__global__ __launch_bounds__(256) void gemm_xproj(
    const __hip_bfloat16* __restrict__ A, const float* __restrict__ W,
    float* __restrict__ part)
{
    __shared__ __align__(16) __hip_bfloat16 As[BM * LDS_STRIDE];
    __shared__ __align__(16) __hip_bfloat16 Ws[BN * LDS_STRIDE];
    const int tid  = threadIdx.x;
    const int bm   = blockIdx.x * BM;
    const int ck   = blockIdx.y;
    const int k0b  = ck * 256;
    const int lane = tid & 63;
    const int wid  = tid >> 6;
    const int wm   = (wid >> 1) * 64;
    const int wn   = (wid & 1) * 64;
    const int l15  = lane & 15;
    const int quad = lane >> 4;

    floatx4 acc[4][4];
#pragma unroll
    for (int i = 0; i < 4; ++i)
#pragma unroll
        for (int j = 0; j < 4; ++j)
#pragma unroll
            for (int r = 0; r < 4; ++r) acc[i][j][r] = 0.f;

    const int lrow = tid >> 3;
    const int lcol = (tid & 7) * 8;

    for (int k0 = k0b; k0 < k0b + 256; k0 += BK) {
#pragma unroll
        for (int r = 0; r < 4; ++r) {
            const int row = r * 32 + lrow;
            const uint4 va = *reinterpret_cast<const uint4*>(A + (size_t)(bm + row) * 2048 + k0 + lcol);
            *reinterpret_cast<uint4*>(&As[row * LDS_STRIDE + lcol]) = va;
            __align__(16) unsigned short wb[8];
            if (row < 96) {
                const float4 f0 = *reinterpret_cast<const float4*>(W + (size_t)row * 2048 + k0 + lcol);
                const float4 f1 = *reinterpret_cast<const float4*>(W + (size_t)row * 2048 + k0 + lcol + 4);
                wb[0] = f2bfbits(f0.x); wb[1] = f2bfbits(f0.y);
                wb[2] = f2bfbits(f0.z); wb[3] = f2bfbits(f0.w);
                wb[4] = f2bfbits(f1.x); wb[5] = f2bfbits(f1.y);
                wb[6] = f2bfbits(f1.z); wb[7] = f2bfbits(f1.w);
            } else {
#pragma unroll
                for (int e = 0; e < 8; ++e) wb[e] = 0;
            }
            *reinterpret_cast<uint4*>(&Ws[row * LDS_STRIDE + lcol]) = *reinterpret_cast<const uint4*>(wb);
        }
        __syncthreads();
#pragma unroll
        for (int kk = 0; kk < BK; kk += 32) {
            short8 af[4], bfr[4];
#pragma unroll
            for (int i = 0; i < 4; ++i)
                af[i] = *reinterpret_cast<const short8*>(&As[(wm + i * 16 + l15) * LDS_STRIDE + kk + quad * 8]);
#pragma unroll
            for (int j = 0; j < 4; ++j)
                bfr[j] = *reinterpret_cast<const short8*>(&Ws[(wn + j * 16 + l15) * LDS_STRIDE + kk + quad * 8]);
#pragma unroll
            for (int i = 0; i < 4; ++i)
#pragma unroll
                for (int j = 0; j < 4; ++j)
                    acc[i][j] = __builtin_amdgcn_mfma_f32_16x16x32_bf16(af[i], bfr[j], acc[i][j], 0, 0, 0);
        }
        __syncthreads();
    }

    float* pp = part + (size_t)ck * (4096 * 96);
#pragma unroll
    for (int i = 0; i < 4; ++i) {
#pragma unroll
        for (int j = 0; j < 4; ++j) {
            const int col = wn + j * 16 + l15;
            if (col < 96) {
#pragma unroll
                for (int r = 0; r < 4; ++r) {
                    const int rowg = bm + wm + i * 16 + quad * 4 + r;
                    pp[(size_t)rowg * 96 + col] = acc[i][j][r];
                }
            }
        }
    }
}

__global__ __launch_bounds__(256) void xproj_reduce(
    const float* __restrict__ part, float* __restrict__ xdblF)
{
    const int idx = blockIdx.x * 256 + threadIdx.x;    // 4096*96 = 393216
    float s = 0.f;
#pragma unroll
    for (int c = 0; c < 8; ++c)
        s += part[(size_t)c * 393216 + idx];
    xdblF[idx] = s;
}

// ---------------- dt GEMM: A = xdblF f32 [4096][96] (k=0..63), W f32 [2048][64], softplus, out [t][d] bf16 ----------------
__global__ __launch_bounds__(256) void gemm_dt64(
    const float* __restrict__ A, const float* __restrict__ W,
    const float* __restrict__ bias, __hip_bfloat16* __restrict__ C)
{
    __shared__ __align__(16) __hip_bfloat16 As[BM * LDS_STRIDE];
    __shared__ __align__(16) __hip_bfloat16 Ws[BN * LDS_STRIDE];
    const int tid  = threadIdx.x;
    const int bm   = blockIdx.x * BM;
    const int bn   = blockIdx.y * BN;
    const int lane = tid & 63;
    const int wid  = tid >> 6;
    const int wm   = (wid >> 1) * 64;
    const int wn   = (wid & 1) * 64;
    const int l15  = lane & 15;
    const int quad = lane >> 4;
    const int lrow = tid >> 3;
    const int lcol = (tid & 7) * 8;

#pragma unroll
    for (int r = 0; r < 4; ++r) {
        const int row = r * 32 + lrow;
        __align__(16) unsigned short ab[8];
        const float4 a0 = *reinterpret_cast<const float4*>(A + (size_t)(bm + row) * 96 + lcol);
        const float4 a1 = *reinterpret_cast<const float4*>(A + (size_t)(bm + row) * 96 + lcol + 4);
        ab[0] = f2bfbits(a0.x); ab[1] = f2bfbits(a0.y);
        ab[2] = f2bfbits(a0.z); ab[3] = f2bfbits(a0.w);
        ab[4] = f2bfbits(a1.x); ab[5] = f2bfbits(a1.y);
        ab[6] = f2bfbits(a1.z); ab[7] = f2bfbits(a1.w);
        *reinterpret_cast<uint4*>(&As[row * LDS_STRIDE + lcol]) = *reinterpret_cast<const uint4*>(ab);

        const int n = bn + row;
        __align__(16) unsigned short wb[8];
        const float4 f0 = *reinterpret_cast<const float4*>(W + (size_t)n * 64 + lcol);
        const float4 f1 = *reinterpret_cast<const float4*>(W + (size_t)n * 64 + lcol + 4);
        wb[0] = f2bfbits(f0.x); wb[1] = f2bfbits(f0.y);
        wb[2] = f2bfbits(f0.z); wb[3] = f2bfbits(f0.w);
        wb[4] = f2bfbits(f1.x); wb[5] = f2bfbits(f1.y);
        wb[6] = f2bfbits(f1.z); wb[7] = f2bfbits(f1.w);
        *reinterpret_cast<uint4*>(&Ws[row * LDS_STRIDE + lcol]) = *reinterpret_cast<const uint4*>(wb);
    }
    __syncthreads();

    floatx4 acc[4][4];
#pragma unroll
    for (int i = 0; i < 4; ++i)
#pragma unroll
        for (int j = 0; j < 4; ++j)
#pragma unroll
            for (int r = 0; r < 4; ++r) acc[i][j][r] = 0.f;

#pragma unroll
    for (int kk = 0; kk < BK; kk += 32) {
        short8 af[4], bfr[4];
#pragma unroll
        for (int i = 0; i < 4; ++i)
            af[i] = *reinterpret_cast<const short8*>(&As[(wm + i * 16 + l15) * LDS_STRIDE + kk + quad * 8]);
#pragma unroll
        for (int j = 0; j < 4; ++j)
            bfr[j] = *reinterpret_cast<const short8*>(&Ws[(wn + j * 16 + l15) * LDS_STRIDE + kk + quad * 8]);
#pragma unroll
        for (int i = 0; i < 4; ++i)
#pragma unroll
            for (int j = 0; j < 4; ++j)
                acc[i][j] = __builtin_amdgcn_mfma_f32_16x16x32_bf16(af[i], bfr[j], acc[i][j], 0, 0, 0);
    }

#pragma unroll
    for (int i = 0; i < 4; ++i) {
#pragma unroll
        for (int j = 0; j < 4; ++j) {
            const int col = bn + wn + j * 16 + l15;
            const float bv = bias[col];
#pragma unroll
            for (int r = 0; r < 4; ++r) {
                const int rowg = bm + wm + i * 16 + quad * 4 + r;
                float v = acc[i][j][r] + bv;
                v = (v > 20.f) ? v : log1pf(__expf(v));
                C[(size_t)rowg * 2048 + col] = __float2bfloat16(v);
            }
        }
    }
}

// ---------------- LayerNorm + residual ----------------
__global__ __launch_bounds__(256) void ln_res_kernel(
    const float* __restrict__ x,
    const float* __restrict__ nw, const float* __restrict__ nb,
    __hip_bfloat16* __restrict__ h, float* __restrict__ res)
{
    const int row = blockIdx.x;
    const int tid = threadIdx.x;
    const float* xr = x + (size_t)row * 1024;
    float v[4];
    float sum = 0.f, sumsq = 0.f;
#pragma unroll
    for (int i = 0; i < 4; ++i) {
        const float f = xr[tid + i * 256];
        v[i] = f; sum += f; sumsq += f * f;
    }
#pragma unroll
    for (int off = 32; off > 0; off >>= 1) {
        sum   += __shfl_down(sum, off);
        sumsq += __shfl_down(sumsq, off);
    }
    __shared__ float ssum[4], ssq[4];
    const int w = tid >> 6, lane = tid & 63;
    if (lane == 0) { ssum[w] = sum; ssq[w] = sumsq; }
    __syncthreads();
    sum   = ssum[0] + ssum[1] + ssum[2] + ssum[3];
    sumsq = ssq[0] + ssq[1] + ssq[2] + ssq[3];
    const float mu  = sum * (1.f / 1024.f);
    const float var = sumsq * (1.f / 1024.f) - mu * mu;
    const float rs  = rsqrtf(var + 1e-5f);
#pragma unroll
    for (int i = 0; i < 4; ++i) {
        const int c = tid + i * 256;
        const float hn = (v[i] - mu) * rs * nw[c] + nb[c];
        h[(size_t)row * 1024 + c]   = __float2bfloat16(hn);
        res[(size_t)row * 1024 + c] = v[i];
    }
}

// ---------------- conv(width4,causal)+SiLU -> u[t,d]; silu(z) -> sz[t,d] (8t x 8d per thread) ----------------
__global__ __launch_bounds__(256) void conv_td(
    const __hip_bfloat16* __restrict__ xz,
    const float* __restrict__ conv_w, const float* __restrict__ conv_b,
    __hip_bfloat16* __restrict__ ub, __hip_bfloat16* __restrict__ szb)
{
    const int t0 = blockIdx.x * 8;          // 512 blocks; 8|2048 so tiles never cross batch
    const int d8 = threadIdx.x * 8;
    const int l0 = t0 & 2047;
    short8 xr[11];
#pragma unroll
    for (int i = 0; i < 11; ++i) {
        short8 v = {0, 0, 0, 0, 0, 0, 0, 0};
        if (l0 + i - 3 >= 0)
            v = *reinterpret_cast<const short8*>(xz + (size_t)(t0 + i - 3) * 4096 + d8);
        xr[i] = v;
    }
    float w[8][4], bias[8];
    {
        const float4* wp = reinterpret_cast<const float4*>(conv_w + (size_t)d8 * 4);
#pragma unroll
        for (int dd = 0; dd < 8; ++dd) {
            const float4 wv = wp[dd];
            w[dd][0] = wv.x; w[dd][1] = wv.y; w[dd][2] = wv.z; w[dd][3] = wv.w;
        }
        const float4* bp = reinterpret_cast<const float4*>(conv_b + d8);
        const float4 b0 = bp[0], b1 = bp[1];
        bias[0] = b0.x; bias[1] = b0.y; bias[2] = b0.z; bias[3] = b0.w;
        bias[4] = b1.x; bias[5] = b1.y; bias[6] = b1.z; bias[7] = b1.w;
    }
#pragma unroll
    for (int tt = 0; tt < 8; ++tt) {
        const short8 zv = *reinterpret_cast<const short8*>(xz + (size_t)(t0 + tt) * 4096 + 2048 + d8);
        __align__(16) unsigned short uo[8], zo[8];
#pragma unroll
        for (int dd = 0; dd < 8; ++dd) {
            float a = bias[dd];
            a = fmaf(bf2f(xr[tt + 0][dd]), w[dd][0], a);
            a = fmaf(bf2f(xr[tt + 1][dd]), w[dd][1], a);
            a = fmaf(bf2f(xr[tt + 2][dd]), w[dd][2], a);
            a = fmaf(bf2f(xr[tt + 3][dd]), w[dd][3], a);
            uo[dd] = f2bfbits(a / (1.f + __expf(-a)));
            const float z = bf2f(zv[dd]);
            zo[dd] = f2bfbits(z / (1.f + __expf(-z)));
        }
        *reinterpret_cast<uint4*>(ub  + (size_t)(t0 + tt) * 2048 + d8) = *reinterpret_cast<const uint4*>(uo);
        *reinterpret_cast<uint4*>(szb + (size_t)(t0 + tt) * 2048 + d8) = *reinterpret_cast<const uint4*>(zo);
    }
}

// ---------------- state-in-lane chunked scan: lane = channel, 16 states in VGPRs ----------------
__global__ __launch_bounds__(256) void scan_phase1(
    const __hip_bfloat16* __restrict__ dtb, const __hip_bfloat16* __restrict__ ub,
    const float* __restrict__ xdblF, const float* __restrict__ A_log,
    __hip_bfloat16* __restrict__ Sbuf, float* __restrict__ sdtb)
{
    const int tid = threadIdx.x;
    const int c   = blockIdx.x >> 4;
    const int bd  = ((blockIdx.x & 15) << 8) + tid;
    const int b   = bd >> 11;
    const int d   = bd & 2047;
    const int row0 = b * 2048 + c * T_CHUNK;

    float As[16];
    {
        const float4* ap = reinterpret_cast<const float4*>(A_log + (size_t)d * 16);
#pragma unroll
        for (int i = 0; i < 4; ++i) {
            const float4 a = ap[i];
            As[4 * i + 0] = -__expf(a.x) * L2E;
            As[4 * i + 1] = -__expf(a.y) * L2E;
            As[4 * i + 2] = -__expf(a.z) * L2E;
            As[4 * i + 3] = -__expf(a.w) * L2E;
        }
    }
    float S[16];
#pragma unroll
    for (int s = 0; s < 16; ++s) S[s] = 0.f;
    float sdt = 0.f;

#pragma unroll 4
    for (int t = 0; t < T_CHUNK; ++t) {
        const size_t row = (size_t)(row0 + t);
        const float dtv = __bfloat162float(dtb[row * 2048 + d]);
        const float uu  = __bfloat162float(ub[row * 2048 + d]);
        const float dtu = dtv * uu;
        sdt += dtv;
        const float4* bq = reinterpret_cast<const float4*>(xdblF + row * 96 + 64);
#pragma unroll
        for (int i = 0; i < 4; ++i) {
            const float4 Bf = bq[i];
            float dA;
            dA = exp2f(dtv * As[4 * i + 0]); S[4 * i + 0] = fmaf(dA, S[4 * i + 0], dtu * Bf.x);
            dA = exp2f(dtv * As[4 * i + 1]); S[4 * i + 1] = fmaf(dA, S[4 * i + 1], dtu * Bf.y);
            dA = exp2f(dtv * As[4 * i + 2]); S[4 * i + 2] = fmaf(dA, S[4 * i + 2], dtu * Bf.z);
            dA = exp2f(dtv * As[4 * i + 3]); S[4 * i + 3] = fmaf(dA, S[4 * i + 3], dtu * Bf.w);
        }
    }
    __align__(16) unsigned short pk[16];
#pragma unroll
    for (int s = 0; s < 16; ++s) pk[s] = f2bfbits(S[s]);
    __hip_bfloat16* sp = Sbuf + ((size_t)c * 4096 + bd) * 16;
    *reinterpret_cast<uint4*>(sp)     = *reinterpret_cast<const uint4*>(pk);
    *reinterpret_cast<uint4*>(sp + 8) = *reinterpret_cast<const uint4*>(pk + 8);
    sdtb[(size_t)c * 4096 + bd] = sdt;
}

__global__ __launch_bounds__(256) void scan_phase2(
    __hip_bfloat16* SH, const float* __restrict__ sdtb, const float* __restrict__ A_log)
{
    const int idx = blockIdx.x * 256 + threadIdx.x;   // 65536
    const int bd = idx >> 4, s = idx & 15;
    const int d = bd & 2047;
    const float As = -__expf(A_log[(size_t)d * 16 + s]) * L2E;
    float h = 0.f;
#pragma unroll 4
    for (int c = 0; c < G_CHUNKS; ++c) {
        const size_t ix = ((size_t)c * 4096 + bd) * 16 + s;
        const float Sv  = __bfloat162float(SH[ix]);
        const float sdt = sdtb[(size_t)c * 4096 + bd];
        SH[ix] = __float2bfloat16(h);
        h = fmaf(exp2f(As * sdt), h, Sv);
    }
}

__global__ __launch_bounds__(256) void scan_phase3(
    const __hip_bfloat16* dtb,
    const __hip_bfloat16* __restrict__ ub, const __hip_bfloat16* __restrict__ szb,
    const float* __restrict__ xdblF, const float* __restrict__ A_log,
    const float* __restrict__ Dw, const __hip_bfloat16* __restrict__ Hinit,
    __hip_bfloat16* yb)
{
    const int tid = threadIdx.x;
    const int c   = blockIdx.x >> 4;
    const int bd  = ((blockIdx.x & 15) << 8) + tid;
    const int b   = bd >> 11;
    const int d   = bd & 2047;
    const int row0 = b * 2048 + c * T_CHUNK;

    float As[16];
    {
        const float4* ap = reinterpret_cast<const float4*>(A_log + (size_t)d * 16);
#pragma unroll
        for (int i = 0; i < 4; ++i) {
            const float4 a = ap[i];
            As[4 * i + 0] = -__expf(a.x) * L2E;
            As[4 * i + 1] = -__expf(a.y) * L2E;
            As[4 * i + 2] = -__expf(a.z) * L2E;
            As[4 * i + 3] = -__expf(a.w) * L2E;
        }
    }
    float h[16];
    {
        const short8* hp = reinterpret_cast<const short8*>(Hinit + ((size_t)c * 4096 + bd) * 16);
        const short8 h0 = hp[0], h1 = hp[1];
#pragma unroll
        for (int s = 0; s < 8; ++s) { h[s] = bf2f(h0[s]); h[8 + s] = bf2f(h1[s]); }
    }
    const float Dv = Dw[d];

    unsigned short dtr[16];
#pragma unroll
    for (int t = 0; t < T_CHUNK; ++t)
        dtr[t] = __builtin_bit_cast(unsigned short, dtb[(size_t)(row0 + t) * 2048 + d]);

#pragma unroll 4
    for (int t = 0; t < T_CHUNK; ++t) {
        const size_t row = (size_t)(row0 + t);
        const float dtv = bf2f((short)dtr[t]);
        const float uu  = __bfloat162float(ub[row * 2048 + d]);
        const float szv = __bfloat162float(szb[row * 2048 + d]);
        const float dtu = dtv * uu;
        const float4* bq = reinterpret_cast<const float4*>(xdblF + row * 96 + 64);
        const float4* cq = reinterpret_cast<const float4*>(xdblF + row * 96 + 80);
        float y0 = 0.f, y1 = 0.f;
#pragma unroll
        for (int i = 0; i < 4; ++i) {
            const float4 Bf = bq[i];
            const float4 Cf = cq[i];
            float dA;
            dA = exp2f(dtv * As[4 * i + 0]); h[4 * i + 0] = fmaf(dA, h[4 * i + 0], dtu * Bf.x); y0 = fmaf(h[4 * i + 0], Cf.x, y0);
            dA = exp2f(dtv * As[4 * i + 1]); h[4 * i + 1] = fmaf(dA, h[4 * i + 1], dtu * Bf.y); y1 = fmaf(h[4 * i + 1], Cf.y, y1);
            dA = exp2f(dtv * As[4 * i + 2]); h[4 * i + 2] = fmaf(dA, h[4 * i + 2], dtu * Bf.z); y0 = fmaf(h[4 * i + 2], Cf.z, y0);
            dA = exp2f(dtv * As[4 * i + 3]); h[4 * i + 3] = fmaf(dA, h[4 * i + 3], dtu * Bf.w); y1 = fmaf(h[4 * i + 3], Cf.w, y1);
        }
        const float yy = fmaf(uu, Dv, y0 + y1) * szv;
        yb[row * 2048 + d] = __float2bfloat16(yy);
    }
}

extern "C" void kernel_launch(void* const* d_in, const int* in_sizes, int n_in,
                              void* d_out, int out_size, void* d_ws, size_t ws_size,
                              hipStream_t stream)
{
    const float* x          = (const float*)d_in[0];
    const float* in_proj_w  = (const float*)d_in[1];
    const float* conv_w     = (const float*)d_in[2];
    const float* conv_b     = (const float*)d_in[3];
    const float* x_proj_w   = (const float*)d_in[4];
    const float* dt_proj_w  = (const float*)d_in[5];
    const float* dt_proj_b  = (const float*)d_in[6];
    const float* A_log      = (const float*)d_in[7];
    const float* Dw         = (const float*)d_in[8];
    const float* out_proj_w = (const float*)d_in[9];
    const float* norm_w     = (const float*)d_in[10];
    const float* norm_b     = (const float*)d_in[11];

    float* out = (float*)d_out;
    float* res = out + 4194304;
    char* ws = (char*)d_ws;
    // Region A [0, 8.39M): h (dead after gemm1) -> xdblF + sdt
    __hip_bfloat16* h      = (__hip_bfloat16*)(ws);                      // 8,388,608 B
    float*          xdblF  = (float*)(ws);                               // 4096*96*4 = 1,572,864
    float*          sdtb   = (float*)(ws + 2359296);                     // 128*4096*4 = 2,097,152 (ends 4,456,448)
    // Region B [8.39M, 41.94M): xz (dead after conv) -> part (dead after reduce) -> dt(+y alias) + S/Hinit
    __hip_bfloat16* xz     = (__hip_bfloat16*)(ws + 8388608);            // 32M
    float*          part   = (float*)(ws + 8388608);                     // 8*4096*96*4 = 12.6M
    __hip_bfloat16* dtb    = (__hip_bfloat16*)(ws + 8388608);            // 16M
    __hip_bfloat16* Sbuf   = (__hip_bfloat16*)(ws + 25165824);           // 16M (Hinit in-place)
    __hip_bfloat16* y      = dtb;                                        // alias (phase3 hoists dt loads)
    // Regions C/D
    __hip_bfloat16* ub     = (__hip_bfloat16*)(ws + 41943040);           // 16M
    __hip_bfloat16* szb    = (__hip_bfloat16*)(ws + 58720256);           // 16M

    // 1. LayerNorm + residual
    ln_res_kernel<<<4096, 256, 0, stream>>>(x, norm_w, norm_b, h, res);
    // 2. xz = h @ in_proj_w^T   (4096x4096x1024)
    gemm_bt<__hip_bfloat16><<<dim3(32, 32), 256, 0, stream>>>(h, in_proj_w, xz, 4096, 1024, 1024, 1024, 4096);
    // 3. u = silu(conv(xz[:,:2048])), sz = silu(xz[:,2048:])   [t,d] layout; xz dead after
    conv_td<<<512, 256, 0, stream>>>(xz, conv_w, conv_b, ub, szb);
    // 4. xdblF = u @ x_proj_w^T  f32 [t][96]: MFMA split-K (8 chunks) + reduce
    gemm_xproj<<<dim3(32, 8), 256, 0, stream>>>(ub, x_proj_w, part);
    xproj_reduce<<<1536, 256, 0, stream>>>(part, xdblF);
    // 5. dt = softplus(xdblF[:, :64] @ dt_proj_w^T + b)  [t][d]
    gemm_dt64<<<dim3(32, 16), 256, 0, stream>>>(xdblF, dt_proj_w, dt_proj_b, dtb);
    // 6. state-in-lane chunked scan (G=128, T=16)
    scan_phase1<<<2048, 256, 0, stream>>>(dtb, ub, xdblF, A_log, Sbuf, sdtb);
    scan_phase2<<<256, 256, 0, stream>>>(Sbuf, sdtb, A_log);
    scan_phase3<<<2048, 256, 0, stream>>>(dtb, ub, szb, xdblF, A_log, Dw, Sbuf, y);
    // 7. out = y @ out_proj_w^T  (4096x1024x2048) -> f32
    gemm_bt<float><<<dim3(32, 8), 256, 0, stream>>>(y, out_proj_w, out, 1024, 2048, 2048, 2048, 1024);
}